// Round 1
// baseline (9437.843 us; speedup 1.0000x reference)
//
#include <hip/hip_runtime.h>
#include <cstdint>
#include <cstddef>

#define B_  128
#define P_  196
#define F_  2048
#define H_  512
#define NF_ 512
#define E_  512
#define V_  10000
#define L_  20
#define T_  19

__device__ __forceinline__ float sigf(float x) { return 1.0f / (1.0f + expf(-x)); }

// ---------------- mean over P ----------------
__global__ __launch_bounds__(256) void mean_kernel(const float* __restrict__ enc,
                                                   float* __restrict__ feat) {
    int b = blockIdx.x >> 3;                       // 8 blocks per batch row (F/256)
    int f = ((blockIdx.x & 7) << 8) + threadIdx.x;
    const float* p = enc + (size_t)b * P_ * F_ + f;
    float s = 0.0f;
    for (int q = 0; q < P_; q++) s += p[(size_t)q * F_];
    feat[b * F_ + f] = s * (1.0f / 196.0f);
}

// ---------------- embedding gather (t < T) ----------------
__global__ __launch_bounds__(256) void gather_kernel(const float* __restrict__ emb,
                                                     const int* __restrict__ gt,
                                                     float* __restrict__ embx) {
    int idx = blockIdx.x * 256 + threadIdx.x;   // B*T*E
    int e = idx & (E_ - 1);
    int bt = idx >> 9;                          // b*T + t
    int b = bt / T_, t = bt - b * T_;
    int tok = gt[b * L_ + t];
    embx[idx] = emb[(size_t)tok * E_ + e];
}

// ---------------- generic fp32 GEMM: C = A(MxK) @ W(NxK)^T, epilogue variants ---
enum { EPI_NONE = 0, EPI_BIAS = 1, EPI_SIGBN = 2, EPI_SIGMUL = 3, EPI_MASK = 4 };

template <int EPI>
__global__ __launch_bounds__(256)
void gemm_xwt(const float* __restrict__ A, int lda,
              const float* __restrict__ W, int ldw,
              const float* __restrict__ bias,
              float* __restrict__ C, long long ldc,
              int M, int N, int K,
              const float* __restrict__ e0,   // SIGBN: gamma | SIGMUL: context (stride ldc)
              const float* __restrict__ e1,   // SIGBN: beta
              const int* __restrict__ clen, int tcur) {
    __shared__ float As[16][65];
    __shared__ float Ws[16][65];
    const int tid = threadIdx.x;
    const int m0 = blockIdx.y << 6;
    const int n0 = blockIdx.x << 6;
    const int row = tid >> 2;            // 0..63
    const int kq  = (tid & 3) << 2;      // 0,4,8,12
    const int ty = tid >> 4, tx = tid & 15;
    float acc[4][4] = {};

    for (int k0 = 0; k0 < K; k0 += 16) {
        float4 av = make_float4(0.f, 0.f, 0.f, 0.f);
        float4 wv = make_float4(0.f, 0.f, 0.f, 0.f);
        int m = m0 + row;
        if (m < M) av = *(const float4*)(A + (size_t)m * lda + k0 + kq);
        int n = n0 + row;
        if (n < N) wv = *(const float4*)(W + (size_t)n * ldw + k0 + kq);
        __syncthreads();
        As[kq + 0][row] = av.x; As[kq + 1][row] = av.y;
        As[kq + 2][row] = av.z; As[kq + 3][row] = av.w;
        Ws[kq + 0][row] = wv.x; Ws[kq + 1][row] = wv.y;
        Ws[kq + 2][row] = wv.z; Ws[kq + 3][row] = wv.w;
        __syncthreads();
#pragma unroll
        for (int k = 0; k < 16; k++) {
            float a[4], w[4];
#pragma unroll
            for (int i = 0; i < 4; i++) a[i] = As[k][(ty << 2) + i];
#pragma unroll
            for (int j = 0; j < 4; j++) w[j] = Ws[k][(tx << 2) + j];
#pragma unroll
            for (int i = 0; i < 4; i++)
#pragma unroll
                for (int j = 0; j < 4; j++)
                    acc[i][j] = fmaf(a[i], w[j], acc[i][j]);
        }
    }

    const float rbn = 1.0f / sqrtf(1.0f + 1e-5f);
#pragma unroll
    for (int i = 0; i < 4; i++) {
        int m = m0 + (ty << 2) + i;
        if (m >= M) continue;
        float rowmask = 1.0f;
        if (EPI == EPI_MASK) rowmask = (tcur < clen[m] - 1) ? 1.0f : 0.0f;
#pragma unroll
        for (int j = 0; j < 4; j++) {
            int n = n0 + (tx << 2) + j;
            if (n >= N) continue;
            float v = acc[i][j];
            if (EPI != EPI_NONE) v += bias[n];
            if (EPI == EPI_SIGBN)  v = e0[n] * (sigf(v) * rbn) + e1[n];
            if (EPI == EPI_SIGMUL) v = sigf(v) * e0[(size_t)m * ldc + n];
            if (EPI == EPI_MASK)   v *= rowmask;
            C[(size_t)m * ldc + n] = v;
        }
    }
}

// ---------------- dual-K gates GEMM: gctx@WihF^T + h@Whh^T ----------------
__global__ __launch_bounds__(256)
void gates_gemm(const float* __restrict__ gctx, const float* __restrict__ Wih,
                const float* __restrict__ h, const float* __restrict__ Whh,
                float* __restrict__ out) {
    __shared__ float As[16][65];
    __shared__ float Ws[16][65];
    const int tid = threadIdx.x;
    const int m0 = blockIdx.y << 6;
    const int n0 = blockIdx.x << 6;
    const int row = tid >> 2;
    const int kq  = (tid & 3) << 2;
    const int ty = tid >> 4, tx = tid & 15;
    float acc[4][4] = {};

    // phase 1: A = gctx (lda=F), W = Wih[:, E:] (ldw=E+F), K = F
    for (int k0 = 0; k0 < F_; k0 += 16) {
        float4 av = *(const float4*)(gctx + (size_t)(m0 + row) * F_ + k0 + kq);
        float4 wv = *(const float4*)(Wih + (size_t)(n0 + row) * (E_ + F_) + E_ + k0 + kq);
        __syncthreads();
        As[kq + 0][row] = av.x; As[kq + 1][row] = av.y;
        As[kq + 2][row] = av.z; As[kq + 3][row] = av.w;
        Ws[kq + 0][row] = wv.x; Ws[kq + 1][row] = wv.y;
        Ws[kq + 2][row] = wv.z; Ws[kq + 3][row] = wv.w;
        __syncthreads();
#pragma unroll
        for (int k = 0; k < 16; k++) {
            float a[4], w[4];
#pragma unroll
            for (int i = 0; i < 4; i++) a[i] = As[k][(ty << 2) + i];
#pragma unroll
            for (int j = 0; j < 4; j++) w[j] = Ws[k][(tx << 2) + j];
#pragma unroll
            for (int i = 0; i < 4; i++)
#pragma unroll
                for (int j = 0; j < 4; j++)
                    acc[i][j] = fmaf(a[i], w[j], acc[i][j]);
        }
    }
    // phase 2: A = h (lda=H), W = Whh (ldw=H), K = H
    for (int k0 = 0; k0 < H_; k0 += 16) {
        float4 av = *(const float4*)(h + (size_t)(m0 + row) * H_ + k0 + kq);
        float4 wv = *(const float4*)(Whh + (size_t)(n0 + row) * H_ + k0 + kq);
        __syncthreads();
        As[kq + 0][row] = av.x; As[kq + 1][row] = av.y;
        As[kq + 2][row] = av.z; As[kq + 3][row] = av.w;
        Ws[kq + 0][row] = wv.x; Ws[kq + 1][row] = wv.y;
        Ws[kq + 2][row] = wv.z; Ws[kq + 3][row] = wv.w;
        __syncthreads();
#pragma unroll
        for (int k = 0; k < 16; k++) {
            float a[4], w[4];
#pragma unroll
            for (int i = 0; i < 4; i++) a[i] = As[k][(ty << 2) + i];
#pragma unroll
            for (int j = 0; j < 4; j++) w[j] = Ws[k][(tx << 2) + j];
#pragma unroll
            for (int i = 0; i < 4; i++)
#pragma unroll
                for (int j = 0; j < 4; j++)
                    acc[i][j] = fmaf(a[i], w[j], acc[i][j]);
        }
    }
#pragma unroll
    for (int i = 0; i < 4; i++) {
        int m = m0 + (ty << 2) + i;
#pragma unroll
        for (int j = 0; j < 4; j++) {
            int n = n0 + (tx << 2) + j;
            out[(size_t)m * (4 * H_) + n] = acc[i][j];
        }
    }
}

// ---------------- attention scores: e[b,p] = sum_n relu(fa + ha) * Wv + bv ----
__global__ __launch_bounds__(256)
void attn_e_kernel(const float* __restrict__ fa, const float* __restrict__ ha,
                   const float* __restrict__ Wv, const float* __restrict__ bv,
                   float* __restrict__ e) {
    int wave = blockIdx.x * 4 + (threadIdx.x >> 6);   // b*P + p
    int lane = threadIdx.x & 63;
    int b = wave / P_;
    const float* fap = fa + (size_t)wave * NF_;
    const float* hap = ha + (size_t)b * NF_;
    float s = 0.0f;
#pragma unroll
    for (int i = 0; i < NF_ / 64; i++) {
        int n = lane + i * 64;
        float v = fap[n] + hap[n];
        v = v > 0.0f ? v : 0.0f;
        s += v * Wv[n];
    }
#pragma unroll
    for (int off = 32; off > 0; off >>= 1) s += __shfl_down(s, off, 64);
    if (lane == 0) e[wave] = s + bv[0];
}

// ---------------- softmax over P (+masked alpha output) ----------------
__global__ __launch_bounds__(256)
void softmax_kernel(const float* __restrict__ e, float* __restrict__ alpha,
                    float* __restrict__ alphas_out, const int* __restrict__ clen,
                    int t) {
    int b = blockIdx.x;
    int p = threadIdx.x;
    __shared__ float red[256];
    float v = (p < P_) ? e[b * P_ + p] : -1e30f;
    red[p] = v;
    __syncthreads();
    for (int s = 128; s > 0; s >>= 1) {
        if (p < s) red[p] = fmaxf(red[p], red[p + s]);
        __syncthreads();
    }
    float mx = red[0];
    __syncthreads();
    float ex = (p < P_) ? expf(v - mx) : 0.0f;
    red[p] = ex;
    __syncthreads();
    for (int s = 128; s > 0; s >>= 1) {
        if (p < s) red[p] += red[p + s];
        __syncthreads();
    }
    float inv = 1.0f / red[0];
    if (p < P_) {
        float a = ex * inv;
        alpha[b * P_ + p] = a;
        float m = (t < clen[b] - 1) ? 1.0f : 0.0f;
        alphas_out[((size_t)b * T_ + t) * P_ + p] = a * m;
    }
}

// ---------------- context: ctx[b,f] = sum_p alpha[b,p] * enc[b,p,f] ----------
__global__ __launch_bounds__(256)
void context_kernel(const float* __restrict__ enc, const float* __restrict__ alpha,
                    float* __restrict__ ctx) {
    __shared__ float al[P_];
    int b = blockIdx.x >> 3;
    int f = ((blockIdx.x & 7) << 8) + threadIdx.x;
    if (threadIdx.x < P_) al[threadIdx.x] = alpha[b * P_ + threadIdx.x];
    __syncthreads();
    const float* ep = enc + (size_t)b * P_ * F_ + f;
    float s = 0.0f;
#pragma unroll 4
    for (int p = 0; p < P_; p++) s = fmaf(al[p], ep[(size_t)p * F_], s);
    ctx[b * F_ + f] = s;
}

// ---------------- LSTM pointwise ----------------
__global__ __launch_bounds__(256)
void lstm_kernel(const float* __restrict__ gatesA, const float* __restrict__ embproj,
                 const float* __restrict__ bih, const float* __restrict__ bhh,
                 float* __restrict__ h, float* __restrict__ c, int t) {
    int idx = blockIdx.x * 256 + threadIdx.x;   // B*H
    int b = idx >> 9, j = idx & (H_ - 1);
    const float* g0 = gatesA + (size_t)b * 4 * H_;
    const float* ep = embproj + ((size_t)b * T_ + t) * 4 * H_;
    float iv = g0[j]            + ep[j]            + bih[j]            + bhh[j];
    float fv = g0[j + H_]       + ep[j + H_]       + bih[j + H_]       + bhh[j + H_];
    float gv = g0[j + 2 * H_]   + ep[j + 2 * H_]   + bih[j + 2 * H_]   + bhh[j + 2 * H_];
    float ov = g0[j + 3 * H_]   + ep[j + 3 * H_]   + bih[j + 3 * H_]   + bhh[j + 3 * H_];
    float cn = sigf(fv) * c[idx] + sigf(iv) * tanhf(gv);
    float hn = sigf(ov) * tanhf(cn);
    c[idx] = cn;
    h[idx] = hn;
}

extern "C" void kernel_launch(void* const* d_in, const int* in_sizes, int n_in,
                              void* d_out, int out_size, void* d_ws, size_t ws_size,
                              hipStream_t stream) {
    const float* enc = (const float*)d_in[0];
    const float* emb = (const float*)d_in[1];
    const float* Wfa = (const float*)d_in[2];
    const float* bfa = (const float*)d_in[3];
    const float* Wha = (const float*)d_in[4];
    const float* bha = (const float*)d_in[5];
    const float* Wv  = (const float*)d_in[6];
    const float* bv  = (const float*)d_in[7];
    const float* Wh0 = (const float*)d_in[8];
    const float* bh0 = (const float*)d_in[9];
    const float* Wc0 = (const float*)d_in[10];
    const float* bc0 = (const float*)d_in[11];
    const float* gh  = (const float*)d_in[12];
    const float* bth = (const float*)d_in[13];
    const float* gc  = (const float*)d_in[14];
    const float* btc = (const float*)d_in[15];
    const float* Wfb = (const float*)d_in[16];
    const float* bfb = (const float*)d_in[17];
    const float* Wih = (const float*)d_in[18];
    const float* Whh = (const float*)d_in[19];
    const float* bih = (const float*)d_in[20];
    const float* bhh = (const float*)d_in[21];
    const float* Wfc = (const float*)d_in[22];
    const float* bfc = (const float*)d_in[23];
    const int* gt   = (const int*)d_in[24];
    const int* clen = (const int*)d_in[25];

    float* out_pred  = (float*)d_out;                       // (B,T,V)
    float* out_alpha = out_pred + (size_t)B_ * T_ * V_;     // (B,T,P)

    float* w = (float*)d_ws;
    float* feat    = w; w += B_ * F_;
    float* hbuf    = w; w += B_ * H_;
    float* cbuf    = w; w += B_ * H_;
    float* habuf   = w; w += B_ * NF_;
    float* ebuf    = w; w += B_ * P_;
    float* alpha   = w; w += B_ * P_;
    float* ctxb    = w; w += B_ * F_;
    float* gctx    = w; w += B_ * F_;
    float* gatesA  = w; w += B_ * 4 * H_;
    float* embx    = w; w += (size_t)B_ * T_ * E_;
    float* embproj = w; w += (size_t)B_ * T_ * 4 * H_;
    float* fatt    = w; w += (size_t)B_ * P_ * NF_;

    // ---- precompute ----
    mean_kernel<<<B_ * 8, 256, 0, stream>>>(enc, feat);
    gemm_xwt<EPI_SIGBN><<<dim3(H_ / 64, B_ / 64), 256, 0, stream>>>(
        feat, F_, Wh0, F_, bh0, hbuf, H_, B_, H_, F_, gh, bth, nullptr, 0);
    gemm_xwt<EPI_SIGBN><<<dim3(H_ / 64, B_ / 64), 256, 0, stream>>>(
        feat, F_, Wc0, F_, bc0, cbuf, H_, B_, H_, F_, gc, btc, nullptr, 0);
    gemm_xwt<EPI_BIAS><<<dim3(NF_ / 64, (B_ * P_) / 64), 256, 0, stream>>>(
        enc, F_, Wfa, F_, bfa, fatt, NF_, B_ * P_, NF_, F_, nullptr, nullptr, nullptr, 0);
    gather_kernel<<<(B_ * T_ * E_) / 256, 256, 0, stream>>>(emb, gt, embx);
    gemm_xwt<EPI_NONE><<<dim3((4 * H_) / 64, (B_ * T_) / 64), 256, 0, stream>>>(
        embx, E_, Wih, E_ + F_, nullptr, embproj, 4 * H_, B_ * T_, 4 * H_, E_,
        nullptr, nullptr, nullptr, 0);

    // ---- recurrent scan ----
    for (int t = 0; t < T_; t++) {
        gemm_xwt<EPI_BIAS><<<dim3(NF_ / 64, B_ / 64), 256, 0, stream>>>(
            hbuf, H_, Wha, H_, bha, habuf, NF_, B_, NF_, H_, nullptr, nullptr, nullptr, 0);
        attn_e_kernel<<<(B_ * P_) / 4, 256, 0, stream>>>(fatt, habuf, Wv, bv, ebuf);
        softmax_kernel<<<B_, 256, 0, stream>>>(ebuf, alpha, out_alpha, clen, t);
        context_kernel<<<B_ * 8, 256, 0, stream>>>(enc, alpha, ctxb);
        gemm_xwt<EPI_SIGMUL><<<dim3(F_ / 64, B_ / 64), 256, 0, stream>>>(
            hbuf, H_, Wfb, H_, bfb, gctx, F_, B_, F_, H_, ctxb, nullptr, nullptr, 0);
        gates_gemm<<<dim3((4 * H_) / 64, B_ / 64), 256, 0, stream>>>(
            gctx, Wih, hbuf, Whh, gatesA);
        lstm_kernel<<<(B_ * H_) / 256, 256, 0, stream>>>(
            gatesA, embproj, bih, bhh, hbuf, cbuf, t);
        gemm_xwt<EPI_MASK><<<dim3((V_ + 63) / 64, B_ / 64), 256, 0, stream>>>(
            hbuf, H_, Wfc, H_, bfc, out_pred + (size_t)t * V_, (long long)T_ * V_,
            B_, V_, H_, nullptr, nullptr, clen, t);
    }
}

// Round 2
// 2773.717 us; speedup vs baseline: 3.4026x; 3.4026x over previous
//
#include <hip/hip_runtime.h>
#include <cstdint>
#include <cstddef>

#define B_  128
#define P_  196
#define F_  2048
#define H_  512
#define NF_ 512
#define E_  512
#define V_  10000
#define L_  20
#define T_  19
#define NPAD_ 10112   // 79*128 padded V for MFMA tiles

typedef short s8v __attribute__((ext_vector_type(8)));
typedef float f32x4 __attribute__((ext_vector_type(4)));

__device__ __forceinline__ float sigf(float x) { return 1.0f / (1.0f + expf(-x)); }
__device__ __forceinline__ ushort f2b(float f) {
    unsigned u = __builtin_bit_cast(unsigned, f);
    u += 0x7fff + ((u >> 16) & 1);          // RNE
    return (ushort)(u >> 16);
}
__device__ __forceinline__ float b2f(ushort h) {
    unsigned u = ((unsigned)h) << 16;
    return __builtin_bit_cast(float, u);
}

// ---------------- cast fp32 matrix -> bf16 (with optional zero row-padding) ---
__global__ __launch_bounds__(256)
void cast_mat(const float* __restrict__ s, ushort* __restrict__ d,
              long long total, int cols, int sld, int srows) {
    long long i4 = ((long long)blockIdx.x * 256 + threadIdx.x) * 4;
    if (i4 >= total) return;
    int n = (int)(i4 / cols);
    int k = (int)(i4 - (long long)n * cols);
    float4 v = make_float4(0.f, 0.f, 0.f, 0.f);
    if (n < srows) v = *(const float4*)(s + (size_t)n * sld + k);
    ushort4 o;
    o.x = f2b(v.x); o.y = f2b(v.y); o.z = f2b(v.z); o.w = f2b(v.w);
    *(ushort4*)(d + i4) = o;
}

// ---------------- mean over P (fp32) ----------------
__global__ __launch_bounds__(256) void mean_kernel(const float* __restrict__ enc,
                                                   float* __restrict__ feat) {
    int b = blockIdx.x >> 3;
    int f = ((blockIdx.x & 7) << 8) + threadIdx.x;
    const float* p = enc + (size_t)b * P_ * F_ + f;
    float s = 0.0f;
    for (int q = 0; q < P_; q++) s += p[(size_t)q * F_];
    feat[b * F_ + f] = s * (1.0f / 196.0f);
}

// ---------------- embedding gather -> bf16 ----------------
__global__ __launch_bounds__(256) void gather_b(const float* __restrict__ emb,
                                                const int* __restrict__ gt,
                                                ushort* __restrict__ embx) {
    int idx = blockIdx.x * 256 + threadIdx.x;   // over B*T*E/4
    int i4 = idx * 4;
    int e = i4 & (E_ - 1);
    int bt = i4 >> 9;
    int b = bt / T_, t = bt - b * T_;
    int tok = gt[b * L_ + t];
    float4 v = *(const float4*)(emb + (size_t)tok * E_ + e);
    ushort4 o;
    o.x = f2b(v.x); o.y = f2b(v.y); o.z = f2b(v.z); o.w = f2b(v.w);
    *(ushort4*)(embx + i4) = o;
}

// ---------------- fp32 GEMM (h0/c0 init + fallback), 64x64 tile -------------
enum { EPI_NONE = 0, EPI_BIAS = 1, EPI_SIGBN = 2, EPI_SIGMUL = 3, EPI_MASK = 4, EPI_BIASB = 5 };

template <int EPI>
__global__ __launch_bounds__(256)
void gemm_xwt(const float* __restrict__ A, int lda,
              const float* __restrict__ W, int ldw,
              const float* __restrict__ bias,
              float* __restrict__ C, long long ldc,
              int M, int N, int K,
              const float* __restrict__ e0, const float* __restrict__ e1,
              const int* __restrict__ clen, int tcur) {
    __shared__ float As[16][65];
    __shared__ float Ws[16][65];
    const int tid = threadIdx.x;
    const int m0 = blockIdx.y << 6;
    const int n0 = blockIdx.x << 6;
    const int row = tid >> 2;
    const int kq  = (tid & 3) << 2;
    const int ty = tid >> 4, tx = tid & 15;
    float acc[4][4] = {};

    for (int k0 = 0; k0 < K; k0 += 16) {
        float4 av = make_float4(0.f, 0.f, 0.f, 0.f);
        float4 wv = make_float4(0.f, 0.f, 0.f, 0.f);
        int m = m0 + row;
        if (m < M) av = *(const float4*)(A + (size_t)m * lda + k0 + kq);
        int n = n0 + row;
        if (n < N) wv = *(const float4*)(W + (size_t)n * ldw + k0 + kq);
        __syncthreads();
        As[kq + 0][row] = av.x; As[kq + 1][row] = av.y;
        As[kq + 2][row] = av.z; As[kq + 3][row] = av.w;
        Ws[kq + 0][row] = wv.x; Ws[kq + 1][row] = wv.y;
        Ws[kq + 2][row] = wv.z; Ws[kq + 3][row] = wv.w;
        __syncthreads();
#pragma unroll
        for (int k = 0; k < 16; k++) {
            float a[4], w[4];
#pragma unroll
            for (int i = 0; i < 4; i++) a[i] = As[k][(ty << 2) + i];
#pragma unroll
            for (int j = 0; j < 4; j++) w[j] = Ws[k][(tx << 2) + j];
#pragma unroll
            for (int i = 0; i < 4; i++)
#pragma unroll
                for (int j = 0; j < 4; j++)
                    acc[i][j] = fmaf(a[i], w[j], acc[i][j]);
        }
    }

    const float rbn = 1.0f / sqrtf(1.0f + 1e-5f);
#pragma unroll
    for (int i = 0; i < 4; i++) {
        int m = m0 + (ty << 2) + i;
        if (m >= M) continue;
        float rowmask = 1.0f;
        if (EPI == EPI_MASK) rowmask = (tcur < clen[m] - 1) ? 1.0f : 0.0f;
#pragma unroll
        for (int j = 0; j < 4; j++) {
            int n = n0 + (tx << 2) + j;
            if (n >= N) continue;
            float v = acc[i][j];
            if (EPI != EPI_NONE) v += bias[n];
            if (EPI == EPI_SIGBN) {
                v = e0[n] * (sigf(v) * rbn) + e1[n];
                C[(size_t)m * ldc + n] = v;
            } else if (EPI == EPI_SIGMUL) {
                C[(size_t)m * ldc + n] = sigf(v) * e0[(size_t)m * ldc + n];
            } else if (EPI == EPI_MASK) {
                C[(size_t)m * ldc + n] = v * rowmask;
            } else if (EPI == EPI_BIASB) {
                ((ushort*)C)[(size_t)m * ldc + n] = f2b(v);
            } else {
                C[(size_t)m * ldc + n] = v;
            }
        }
    }
}

// ---------------- bf16 MFMA GEMM: C = A(MxK) @ W(NxK)^T ----------------
// BN = 128 fixed, BK = 32, 4 waves in 2x2, each wave (BM/2) x 64.
enum { MEPI_NONE = 0, MEPI_BIAS = 1, MEPI_BIASB = 2, MEPI_SIGMUL = 3, MEPI_MASK = 4 };

__device__ __forceinline__ void stage_tile(const ushort* __restrict__ g, int ld,
                                           int row0, int k0, ushort* lds,
                                           int rows, int w, int l) {
    int nchunk = rows >> 4;                  // 1024 B (16 rows) per chunk
    for (int c = w; c < nchunk; c += 4) {
        int flat = c * 1024 + l * 16;        // byte offset in tile
        int r = flat >> 6;                   // row (64 B per row)
        int ce = (flat & 63) >> 1;           // element offset in row
        const ushort* gp = g + (size_t)(row0 + r) * ld + (k0 + ce);
        __builtin_amdgcn_global_load_lds(
            (const __attribute__((address_space(1))) void*)gp,
            (__attribute__((address_space(3))) void*)(lds + c * 512),  // wave-uniform base
            16, 0, 0);
    }
}

template <int BM, int EPI, int DUAL>
__global__ __launch_bounds__(256)
void mfma_gemm(const ushort* __restrict__ A1, int lda1,
               const ushort* __restrict__ W1, int ldw1, int K1,
               const ushort* __restrict__ A2, int lda2,
               const ushort* __restrict__ W2, int ldw2, int K2,
               const float* __restrict__ bias, void* __restrict__ Cout, long long ldc,
               int M, int N,
               const float* __restrict__ ctx, long long ldctx,
               const int* __restrict__ clen, int tcur) {
    __shared__ ushort As[BM * 32];
    __shared__ ushort Bs[128 * 32];
    const int tid = threadIdx.x;
    const int w = tid >> 6, l = tid & 63;
    const int wr = w >> 1, wc = w & 1;
    constexpr int WM = BM / 2;
    constexpr int AF = WM / 16;
    const int m0 = blockIdx.y * BM;
    const int n0 = blockIdx.x * 128;
    const int lrow = l & 15, lk8 = (l >> 4) * 8;
    const int kz = blockIdx.z, nzz = gridDim.z;

    f32x4 acc[AF][4] = {};

    for (int pass = 0; pass < 1 + DUAL; pass++) {
        const ushort* A = pass ? A2 : A1;
        const ushort* W = pass ? W2 : W1;
        const int lda = pass ? lda2 : lda1;
        const int ldw = pass ? ldw2 : ldw1;
        const int K  = pass ? K2 : K1;
        const int chunk = K / nzz;
        const int kbeg = kz * chunk;
        const int kend = kbeg + chunk;
        for (int k0 = kbeg; k0 < kend; k0 += 32) {
            __syncthreads();
            stage_tile(A, lda, m0, k0, As, BM, w, l);
            stage_tile(W, ldw, n0, k0, Bs, 128, w, l);
            __syncthreads();
            s8v af[AF], bf[4];
#pragma unroll
            for (int i = 0; i < AF; i++)
                af[i] = *(const s8v*)(As + (wr * WM + i * 16 + lrow) * 32 + lk8);
#pragma unroll
            for (int j = 0; j < 4; j++)
                bf[j] = *(const s8v*)(Bs + (wc * 64 + j * 16 + lrow) * 32 + lk8);
#pragma unroll
            for (int i = 0; i < AF; i++)
#pragma unroll
                for (int j = 0; j < 4; j++)
                    acc[i][j] = __builtin_amdgcn_mfma_f32_16x16x32_bf16(
                        af[i], bf[j], acc[i][j], 0, 0, 0);
        }
    }

    float* Cz = (float*)Cout + (size_t)kz * (size_t)M * ldc;  // z-partials (MEPI_NONE)
#pragma unroll
    for (int i = 0; i < AF; i++) {
        int rb = m0 + wr * WM + i * 16 + (l >> 4) * 4;
#pragma unroll
        for (int j = 0; j < 4; j++) {
            int n = n0 + wc * 64 + j * 16 + (l & 15);
            if (n >= N) continue;
#pragma unroll
            for (int r = 0; r < 4; r++) {
                int m = rb + r;
                float v = acc[i][j][r];
                if (EPI == MEPI_NONE) {
                    Cz[(size_t)m * ldc + n] = v;
                } else if (EPI == MEPI_BIAS) {
                    ((float*)Cout)[(size_t)m * ldc + n] = v + bias[n];
                } else if (EPI == MEPI_BIASB) {
                    ((ushort*)Cout)[(size_t)m * ldc + n] = f2b(v + bias[n]);
                } else if (EPI == MEPI_SIGMUL) {
                    ((ushort*)Cout)[(size_t)m * ldc + n] =
                        f2b(sigf(v + bias[n]) * ctx[(size_t)m * ldctx + n]);
                } else if (EPI == MEPI_MASK) {
                    float mk = (tcur < clen[m] - 1) ? 1.0f : 0.0f;
                    ((float*)Cout)[(size_t)m * ldc + n] = (v + bias[n]) * mk;
                }
            }
        }
    }
}

// ---------------- attention scores over bf16 fatt ----------------
__global__ __launch_bounds__(256)
void attn_e_b(const ushort* __restrict__ fa, const float* __restrict__ ha,
              const float* __restrict__ Wv, const float* __restrict__ bv,
              float* __restrict__ e) {
    int wave = blockIdx.x * 4 + (threadIdx.x >> 6);   // b*P + p
    int l = threadIdx.x & 63;
    int b = wave / P_;
    const ushort* fap = fa + (size_t)wave * NF_;
    const float* hap = ha + (size_t)b * NF_;
    float s = 0.0f;
#pragma unroll
    for (int i = 0; i < 2; i++) {
        int n = (i * 64 + l) * 4;
        ushort4 u = *(const ushort4*)(fap + n);
        float4 h4 = *(const float4*)(hap + n);
        float4 w4 = *(const float4*)(Wv + n);
        float v;
        v = b2f(u.x) + h4.x; v = v > 0.f ? v : 0.f; s = fmaf(v, w4.x, s);
        v = b2f(u.y) + h4.y; v = v > 0.f ? v : 0.f; s = fmaf(v, w4.y, s);
        v = b2f(u.z) + h4.z; v = v > 0.f ? v : 0.f; s = fmaf(v, w4.z, s);
        v = b2f(u.w) + h4.w; v = v > 0.f ? v : 0.f; s = fmaf(v, w4.w, s);
    }
#pragma unroll
    for (int off = 32; off > 0; off >>= 1) s += __shfl_down(s, off, 64);
    if (l == 0) e[wave] = s + bv[0];
}

// ---------------- softmax over P (+masked alpha output) ----------------
__global__ __launch_bounds__(256)
void softmax_kernel(const float* __restrict__ e, float* __restrict__ alpha,
                    float* __restrict__ alphas_out, const int* __restrict__ clen,
                    int t) {
    int b = blockIdx.x;
    int p = threadIdx.x;
    __shared__ float red[256];
    float v = (p < P_) ? e[b * P_ + p] : -1e30f;
    red[p] = v;
    __syncthreads();
    for (int s = 128; s > 0; s >>= 1) {
        if (p < s) red[p] = fmaxf(red[p], red[p + s]);
        __syncthreads();
    }
    float mx = red[0];
    __syncthreads();
    float ex = (p < P_) ? expf(v - mx) : 0.0f;
    red[p] = ex;
    __syncthreads();
    for (int s = 128; s > 0; s >>= 1) {
        if (p < s) red[p] += red[p + s];
        __syncthreads();
    }
    float inv = 1.0f / red[0];
    if (p < P_) {
        float a = ex * inv;
        alpha[b * P_ + p] = a;
        float m = (t < clen[b] - 1) ? 1.0f : 0.0f;
        alphas_out[((size_t)b * T_ + t) * P_ + p] = a * m;
    }
}

// ---------------- context over bf16 enc ----------------
__global__ __launch_bounds__(256)
void context_b(const ushort* __restrict__ encb, const float* __restrict__ alpha,
               float* __restrict__ ctx) {
    __shared__ float al[P_];
    int b = blockIdx.x >> 1;
    int f0 = ((blockIdx.x & 1) << 10) + threadIdx.x * 4;
    if (threadIdx.x < P_) al[threadIdx.x] = alpha[b * P_ + threadIdx.x];
    __syncthreads();
    const ushort* ep = encb + (size_t)b * P_ * F_ + f0;
    float s0 = 0.f, s1 = 0.f, s2 = 0.f, s3 = 0.f;
#pragma unroll 2
    for (int p = 0; p < P_; p++) {
        ushort4 u = *(const ushort4*)(ep + (size_t)p * F_);
        float a = al[p];
        s0 = fmaf(a, b2f(u.x), s0);
        s1 = fmaf(a, b2f(u.y), s1);
        s2 = fmaf(a, b2f(u.z), s2);
        s3 = fmaf(a, b2f(u.w), s3);
    }
    *(float4*)(ctx + (size_t)b * F_ + f0) = make_float4(s0, s1, s2, s3);
}

// ---------------- context over fp32 enc (fallback) ----------------
__global__ __launch_bounds__(256)
void context_kernel(const float* __restrict__ enc, const float* __restrict__ alpha,
                    float* __restrict__ ctx) {
    __shared__ float al[P_];
    int b = blockIdx.x >> 3;
    int f = ((blockIdx.x & 7) << 8) + threadIdx.x;
    if (threadIdx.x < P_) al[threadIdx.x] = alpha[b * P_ + threadIdx.x];
    __syncthreads();
    const float* ep = enc + (size_t)b * P_ * F_ + f;
    float s = 0.0f;
#pragma unroll 4
    for (int p = 0; p < P_; p++) s = fmaf(al[p], ep[(size_t)p * F_], s);
    ctx[b * F_ + f] = s;
}

// ---------------- LSTM pointwise (sums nz gate partials) ----------------
__global__ __launch_bounds__(256)
void lstm_kernel(const float* __restrict__ gatesA, const float* __restrict__ embproj,
                 const float* __restrict__ bih, const float* __restrict__ bhh,
                 float* __restrict__ h, float* __restrict__ c, ushort* __restrict__ hb,
                 int t, int nz) {
    int idx = blockIdx.x * 256 + threadIdx.x;   // B*H
    int b = idx >> 9, j = idx & (H_ - 1);
    const float* ep = embproj + ((size_t)b * T_ + t) * 4 * H_;
    float g4[4];
#pragma unroll
    for (int q = 0; q < 4; q++) {
        int col = j + q * H_;
        float s = ep[col] + bih[col] + bhh[col];
        for (int z = 0; z < nz; z++)
            s += gatesA[((size_t)z * B_ + b) * 4 * H_ + col];
        g4[q] = s;
    }
    float cn = sigf(g4[1]) * c[idx] + sigf(g4[0]) * tanhf(g4[2]);
    float hn = sigf(g4[3]) * tanhf(cn);
    c[idx] = cn;
    h[idx] = hn;
    hb[idx] = f2b(hn);
}

extern "C" void kernel_launch(void* const* d_in, const int* in_sizes, int n_in,
                              void* d_out, int out_size, void* d_ws, size_t ws_size,
                              hipStream_t stream) {
    const float* enc = (const float*)d_in[0];
    const float* emb = (const float*)d_in[1];
    const float* Wfa = (const float*)d_in[2];
    const float* bfa = (const float*)d_in[3];
    const float* Wha = (const float*)d_in[4];
    const float* bha = (const float*)d_in[5];
    const float* Wv  = (const float*)d_in[6];
    const float* bv  = (const float*)d_in[7];
    const float* Wh0 = (const float*)d_in[8];
    const float* bh0 = (const float*)d_in[9];
    const float* Wc0 = (const float*)d_in[10];
    const float* bc0 = (const float*)d_in[11];
    const float* gh  = (const float*)d_in[12];
    const float* bth = (const float*)d_in[13];
    const float* gc  = (const float*)d_in[14];
    const float* btc = (const float*)d_in[15];
    const float* Wfb = (const float*)d_in[16];
    const float* bfb = (const float*)d_in[17];
    const float* Wih = (const float*)d_in[18];
    const float* Whh = (const float*)d_in[19];
    const float* bih = (const float*)d_in[20];
    const float* bhh = (const float*)d_in[21];
    const float* Wfc = (const float*)d_in[22];
    const float* bfc = (const float*)d_in[23];
    const int* gt   = (const int*)d_in[24];
    const int* clen = (const int*)d_in[25];

    float* out_pred  = (float*)d_out;                       // (B,T,V)
    float* out_alpha = out_pred + (size_t)B_ * T_ * V_;     // (B,T,P)

    char* wp = (char*)d_ws;
    auto alloc = [&](size_t bytes) {
        char* p = wp;
        wp += (bytes + 255) & ~(size_t)255;
        return p;
    };
    float*  feat    = (float*)alloc((size_t)B_ * F_ * 4);
    float*  hbuf    = (float*)alloc((size_t)B_ * H_ * 4);
    float*  cbuf    = (float*)alloc((size_t)B_ * H_ * 4);
    float*  habuf   = (float*)alloc((size_t)B_ * NF_ * 4);
    float*  ebuf    = (float*)alloc((size_t)B_ * P_ * 4);
    float*  alphab  = (float*)alloc((size_t)B_ * P_ * 4);
    float*  ctxb    = (float*)alloc((size_t)B_ * F_ * 4);
    float*  gatesA  = (float*)alloc((size_t)4 * B_ * 4 * H_ * 4);
    float*  embproj = (float*)alloc((size_t)B_ * T_ * 4 * H_ * 4);
    ushort* hb      = (ushort*)alloc((size_t)B_ * H_ * 2);
    ushort* gctxb   = (ushort*)alloc((size_t)B_ * F_ * 2);
    ushort* embxb   = (ushort*)alloc((size_t)B_ * T_ * E_ * 2);
    ushort* fattb   = (ushort*)alloc((size_t)B_ * P_ * NF_ * 2);
    ushort* Wfab    = (ushort*)alloc((size_t)NF_ * F_ * 2);
    ushort* WihEb   = (ushort*)alloc((size_t)4 * H_ * E_ * 2);
    ushort* WihFb   = (ushort*)alloc((size_t)4 * H_ * F_ * 2);
    ushort* Whhb    = (ushort*)alloc((size_t)4 * H_ * H_ * 2);
    ushort* Wfbb    = (ushort*)alloc((size_t)F_ * H_ * 2);
    ushort* Whab    = (ushort*)alloc((size_t)NF_ * H_ * 2);
    ushort* Wfcb    = (ushort*)alloc((size_t)NPAD_ * H_ * 2);
    ushort* encb    = (ushort*)alloc((size_t)B_ * P_ * F_ * 2);
    const bool big = ((size_t)(wp - (char*)d_ws) <= ws_size);

    auto castM = [&](const float* s, ushort* d, long long rows, int cols, int sld, int srows) {
        long long total = rows * (long long)cols;
        cast_mat<<<(int)(total / 1024), 256, 0, stream>>>(s, d, total, cols, sld, srows);
    };

    // ---- one-time casts ----
    if (big) castM(enc, encb, (long long)B_ * P_, F_, F_, B_ * P_);
    castM(Wfa, Wfab, NF_, F_, F_, NF_);
    castM(Wih, WihEb, 4 * H_, E_, E_ + F_, 4 * H_);
    castM(Wih + E_, WihFb, 4 * H_, F_, E_ + F_, 4 * H_);
    castM(Whh, Whhb, 4 * H_, H_, H_, 4 * H_);
    castM(Wfb, Wfbb, F_, H_, H_, F_);
    castM(Wha, Whab, NF_, H_, H_, NF_);
    castM(Wfc, Wfcb, NPAD_, H_, H_, V_);

    // ---- init state ----
    mean_kernel<<<B_ * 8, 256, 0, stream>>>(enc, feat);
    gemm_xwt<EPI_SIGBN><<<dim3(H_ / 64, B_ / 64), 256, 0, stream>>>(
        feat, F_, Wh0, F_, bh0, hbuf, H_, B_, H_, F_, gh, bth, nullptr, 0);
    gemm_xwt<EPI_SIGBN><<<dim3(H_ / 64, B_ / 64), 256, 0, stream>>>(
        feat, F_, Wc0, F_, bc0, cbuf, H_, B_, H_, F_, gc, btc, nullptr, 0);
    castM(hbuf, hb, B_, H_, H_, B_);
    gather_b<<<(B_ * T_ * E_) / 1024, 256, 0, stream>>>(emb, gt, embxb);

    // ---- feat_att (bf16 out) ----
    if (big) {
        mfma_gemm<128, MEPI_BIASB, 0><<<dim3(NF_ / 128, (B_ * P_) / 128, 1), 256, 0, stream>>>(
            encb, F_, Wfab, F_, F_, nullptr, 0, nullptr, 0, 0,
            bfa, fattb, NF_, B_ * P_, NF_, nullptr, 0, nullptr, 0);
    } else {
        gemm_xwt<EPI_BIASB><<<dim3(NF_ / 64, (B_ * P_) / 64), 256, 0, stream>>>(
            enc, F_, Wfa, F_, bfa, (float*)fattb, NF_, B_ * P_, NF_, F_,
            nullptr, nullptr, nullptr, 0);
    }
    // ---- embproj = embx @ WihE^T (fp32 out) ----
    mfma_gemm<128, MEPI_NONE, 0><<<dim3((4 * H_) / 128, (B_ * T_) / 128, 1), 256, 0, stream>>>(
        embxb, E_, WihEb, E_, E_, nullptr, 0, nullptr, 0, 0,
        nullptr, embproj, 4 * H_, B_ * T_, 4 * H_, nullptr, 0, nullptr, 0);

    // ---- recurrent scan ----
    for (int t = 0; t < T_; t++) {
        mfma_gemm<32, MEPI_BIAS, 0><<<dim3(NF_ / 128, B_ / 32, 1), 256, 0, stream>>>(
            hb, H_, Whab, H_, H_, nullptr, 0, nullptr, 0, 0,
            bha, habuf, NF_, B_, NF_, nullptr, 0, nullptr, 0);
        attn_e_b<<<(B_ * P_) / 4, 256, 0, stream>>>(fattb, habuf, Wv, bv, ebuf);
        softmax_kernel<<<B_, 256, 0, stream>>>(ebuf, alphab, out_alpha, clen, t);
        if (big) context_b<<<B_ * 2, 256, 0, stream>>>(encb, alphab, ctxb);
        else     context_kernel<<<B_ * 8, 256, 0, stream>>>(enc, alphab, ctxb);
        mfma_gemm<32, MEPI_SIGMUL, 0><<<dim3(F_ / 128, B_ / 32, 1), 256, 0, stream>>>(
            hb, H_, Wfbb, H_, H_, nullptr, 0, nullptr, 0, 0,
            bfb, gctxb, F_, B_, F_, ctxb, F_, nullptr, 0);
        mfma_gemm<32, MEPI_NONE, 1><<<dim3((4 * H_) / 128, B_ / 32, 4), 256, 0, stream>>>(
            gctxb, F_, WihFb, F_, F_, hb, H_, Whhb, H_, H_,
            nullptr, gatesA, 4 * H_, B_, 4 * H_, nullptr, 0, nullptr, 0);
        lstm_kernel<<<(B_ * H_) / 256, 256, 0, stream>>>(
            gatesA, embproj, bih, bhh, hbuf, cbuf, hb, t, 4);
        mfma_gemm<64, MEPI_MASK, 0><<<dim3(NPAD_ / 128, B_ / 64, 1), 256, 0, stream>>>(
            hb, H_, Wfcb, H_, H_, nullptr, 0, nullptr, 0, 0,
            bfc, out_pred + (size_t)t * V_, (long long)T_ * V_, B_, V_,
            nullptr, 0, clen, t);
    }
}

// Round 3
// 2570.436 us; speedup vs baseline: 3.6717x; 1.0791x over previous
//
#include <hip/hip_runtime.h>
#include <cstdint>
#include <cstddef>

#define B_  128
#define P_  196
#define F_  2048
#define H_  512
#define NF_ 512
#define E_  512
#define V_  10000
#define L_  20
#define T_  19
#define NPAD_ 10112   // 79*128 padded V for MFMA tiles

typedef short s8v __attribute__((ext_vector_type(8)));
typedef float f32x4 __attribute__((ext_vector_type(4)));

__device__ __forceinline__ float sigf(float x) { return 1.0f / (1.0f + expf(-x)); }
__device__ __forceinline__ ushort f2b(float f) {
    unsigned u = __builtin_bit_cast(unsigned, f);
    u += 0x7fff + ((u >> 16) & 1);          // RNE
    return (ushort)(u >> 16);
}
__device__ __forceinline__ float b2f(ushort h) {
    unsigned u = ((unsigned)h) << 16;
    return __builtin_bit_cast(float, u);
}

// ---------------- cast fp32 matrix -> bf16 (with optional zero row-padding) ---
__global__ __launch_bounds__(256)
void cast_mat(const float* __restrict__ s, ushort* __restrict__ d,
              long long total, int cols, int sld, int srows) {
    long long i4 = ((long long)blockIdx.x * 256 + threadIdx.x) * 4;
    if (i4 >= total) return;
    int n = (int)(i4 / cols);
    int k = (int)(i4 - (long long)n * cols);
    float4 v = make_float4(0.f, 0.f, 0.f, 0.f);
    if (n < srows) v = *(const float4*)(s + (size_t)n * sld + k);
    ushort4 o;
    o.x = f2b(v.x); o.y = f2b(v.y); o.z = f2b(v.z); o.w = f2b(v.w);
    *(ushort4*)(d + i4) = o;
}

// ---------------- mean over P (fp32) ----------------
__global__ __launch_bounds__(256) void mean_kernel(const float* __restrict__ enc,
                                                   float* __restrict__ feat) {
    int b = blockIdx.x >> 3;
    int f = ((blockIdx.x & 7) << 8) + threadIdx.x;
    const float* p = enc + (size_t)b * P_ * F_ + f;
    float s = 0.0f;
    for (int q = 0; q < P_; q++) s += p[(size_t)q * F_];
    feat[b * F_ + f] = s * (1.0f / 196.0f);
}

// ---------------- embedding gather -> bf16 ----------------
__global__ __launch_bounds__(256) void gather_b(const float* __restrict__ emb,
                                                const int* __restrict__ gt,
                                                ushort* __restrict__ embx) {
    int idx = blockIdx.x * 256 + threadIdx.x;   // over B*T*E/4
    int i4 = idx * 4;
    int e = i4 & (E_ - 1);
    int bt = i4 >> 9;
    int b = bt / T_, t = bt - b * T_;
    int tok = gt[b * L_ + t];
    float4 v = *(const float4*)(emb + (size_t)tok * E_ + e);
    ushort4 o;
    o.x = f2b(v.x); o.y = f2b(v.y); o.z = f2b(v.z); o.w = f2b(v.w);
    *(ushort4*)(embx + i4) = o;
}

// ---------------- fp32 GEMM (fallback only), 64x64 tile -------------
enum { EPI_NONE = 0, EPI_BIAS = 1, EPI_BIASB = 5 };

template <int EPI>
__global__ __launch_bounds__(256)
void gemm_xwt(const float* __restrict__ A, int lda,
              const float* __restrict__ W, int ldw,
              const float* __restrict__ bias,
              float* __restrict__ C, long long ldc,
              int M, int N, int K) {
    __shared__ float As[16][65];
    __shared__ float Ws[16][65];
    const int tid = threadIdx.x;
    const int m0 = blockIdx.y << 6;
    const int n0 = blockIdx.x << 6;
    const int row = tid >> 2;
    const int kq  = (tid & 3) << 2;
    const int ty = tid >> 4, tx = tid & 15;
    float acc[4][4] = {};

    for (int k0 = 0; k0 < K; k0 += 16) {
        float4 av = make_float4(0.f, 0.f, 0.f, 0.f);
        float4 wv = make_float4(0.f, 0.f, 0.f, 0.f);
        int m = m0 + row;
        if (m < M) av = *(const float4*)(A + (size_t)m * lda + k0 + kq);
        int n = n0 + row;
        if (n < N) wv = *(const float4*)(W + (size_t)n * ldw + k0 + kq);
        __syncthreads();
        As[kq + 0][row] = av.x; As[kq + 1][row] = av.y;
        As[kq + 2][row] = av.z; As[kq + 3][row] = av.w;
        Ws[kq + 0][row] = wv.x; Ws[kq + 1][row] = wv.y;
        Ws[kq + 2][row] = wv.z; Ws[kq + 3][row] = wv.w;
        __syncthreads();
#pragma unroll
        for (int k = 0; k < 16; k++) {
            float a[4], w[4];
#pragma unroll
            for (int i = 0; i < 4; i++) a[i] = As[k][(ty << 2) + i];
#pragma unroll
            for (int j = 0; j < 4; j++) w[j] = Ws[k][(tx << 2) + j];
#pragma unroll
            for (int i = 0; i < 4; i++)
#pragma unroll
                for (int j = 0; j < 4; j++)
                    acc[i][j] = fmaf(a[i], w[j], acc[i][j]);
        }
    }

#pragma unroll
    for (int i = 0; i < 4; i++) {
        int m = m0 + (ty << 2) + i;
        if (m >= M) continue;
#pragma unroll
        for (int j = 0; j < 4; j++) {
            int n = n0 + (tx << 2) + j;
            if (n >= N) continue;
            float v = acc[i][j];
            if (EPI != EPI_NONE) v += bias[n];
            if (EPI == EPI_BIASB) ((ushort*)C)[(size_t)m * ldc + n] = f2b(v);
            else                  C[(size_t)m * ldc + n] = v;
        }
    }
}

// ---------------- bf16 MFMA GEMM: C = A(MxK) @ W(NxK)^T ----------------
// BN = 128 fixed, BK = 32, 4 waves in 2x2, each wave (BM/2) x 64.
enum { MEPI_NONE = 0, MEPI_BIAS = 1, MEPI_BIASB = 2, MEPI_MASK = 4 };

__device__ __forceinline__ void stage_tile(const ushort* __restrict__ g, int ld,
                                           int row0, int k0, ushort* lds,
                                           int rows, int w, int l) {
    int nchunk = rows >> 4;                  // 1024 B (16 rows) per chunk
    for (int c = w; c < nchunk; c += 4) {
        int flat = c * 1024 + l * 16;        // byte offset in tile
        int r = flat >> 6;                   // row (64 B per row)
        int ce = (flat & 63) >> 1;           // element offset in row
        const ushort* gp = g + (size_t)(row0 + r) * ld + (k0 + ce);
        __builtin_amdgcn_global_load_lds(
            (const __attribute__((address_space(1))) void*)gp,
            (__attribute__((address_space(3))) void*)(lds + c * 512),  // wave-uniform base
            16, 0, 0);
    }
}

template <int BM, int EPI, int DUAL>
__global__ __launch_bounds__(256)
void mfma_gemm(const ushort* __restrict__ A1, int lda1,
               const ushort* __restrict__ W1, int ldw1, int K1,
               const ushort* __restrict__ A2, int lda2,
               const ushort* __restrict__ W2, int ldw2, int K2,
               const float* __restrict__ bias, void* __restrict__ Cout, long long ldc,
               int M, int N,
               const int* __restrict__ clen, int tcur) {
    __shared__ ushort As[BM * 32];
    __shared__ ushort Bs[128 * 32];
    const int tid = threadIdx.x;
    const int w = tid >> 6, l = tid & 63;
    const int wr = w >> 1, wc = w & 1;
    constexpr int WM = BM / 2;
    constexpr int AF = WM / 16;
    const int m0 = blockIdx.y * BM;
    const int n0 = blockIdx.x * 128;
    const int lrow = l & 15, lk8 = (l >> 4) * 8;
    const int kz = blockIdx.z, nzz = gridDim.z;

    f32x4 acc[AF][4] = {};

    for (int pass = 0; pass < 1 + DUAL; pass++) {
        const ushort* A = pass ? A2 : A1;
        const ushort* W = pass ? W2 : W1;
        const int lda = pass ? lda2 : lda1;
        const int ldw = pass ? ldw2 : ldw1;
        const int K  = pass ? K2 : K1;
        const int chunk = K / nzz;
        const int kbeg = kz * chunk;
        const int kend = kbeg + chunk;
        for (int k0 = kbeg; k0 < kend; k0 += 32) {
            __syncthreads();
            stage_tile(A, lda, m0, k0, As, BM, w, l);
            stage_tile(W, ldw, n0, k0, Bs, 128, w, l);
            __syncthreads();
            s8v af[AF], bf[4];
#pragma unroll
            for (int i = 0; i < AF; i++)
                af[i] = *(const s8v*)(As + (wr * WM + i * 16 + lrow) * 32 + lk8);
#pragma unroll
            for (int j = 0; j < 4; j++)
                bf[j] = *(const s8v*)(Bs + (wc * 64 + j * 16 + lrow) * 32 + lk8);
#pragma unroll
            for (int i = 0; i < AF; i++)
#pragma unroll
                for (int j = 0; j < 4; j++)
                    acc[i][j] = __builtin_amdgcn_mfma_f32_16x16x32_bf16(
                        af[i], bf[j], acc[i][j], 0, 0, 0);
        }
    }

    float* Cz = (float*)Cout + (size_t)kz * (size_t)M * ldc;  // z-partials (MEPI_NONE)
#pragma unroll
    for (int i = 0; i < AF; i++) {
        int rb = m0 + wr * WM + i * 16 + (l >> 4) * 4;
#pragma unroll
        for (int j = 0; j < 4; j++) {
            int n = n0 + wc * 64 + j * 16 + (l & 15);
            if (n >= N) continue;
#pragma unroll
            for (int r = 0; r < 4; r++) {
                int m = rb + r;
                float v = acc[i][j][r];
                if (EPI == MEPI_NONE) {
                    Cz[(size_t)m * ldc + n] = v;
                } else if (EPI == MEPI_BIAS) {
                    ((float*)Cout)[(size_t)m * ldc + n] = v + bias[n];
                } else if (EPI == MEPI_BIASB) {
                    ((ushort*)Cout)[(size_t)m * ldc + n] = f2b(v + bias[n]);
                } else if (EPI == MEPI_MASK) {
                    float mk = (tcur < clen[m] - 1) ? 1.0f : 0.0f;
                    ((float*)Cout)[(size_t)m * ldc + n] = (v + bias[n]) * mk;
                }
            }
        }
    }
}

// ---------------- h0/c0 finalize: sum z-partials, sigmoid+BN ----------------
__global__ __launch_bounds__(256)
void h0c0_final(const float* __restrict__ part,   // 4 x B x 1024
                const float* __restrict__ b0,     // bh0 | bc0
                const float* __restrict__ g0,     // gamma_h | gamma_c
                const float* __restrict__ bt0,    // beta_h | beta_c
                float* __restrict__ cbuf, ushort* __restrict__ hb) {
    int idx = blockIdx.x * 256 + threadIdx.x;   // B*512
    int b = idx >> 9, j = idx & 511;
    const float rbn = 1.0f / sqrtf(1.0f + 1e-5f);
    float sh = b0[j], sc = b0[j + 512];
    for (int z = 0; z < 4; z++) {
        sh += part[((size_t)z * B_ + b) * 1024 + j];
        sc += part[((size_t)z * B_ + b) * 1024 + j + 512];
    }
    float hv = g0[j] * (sigf(sh) * rbn) + bt0[j];
    float cv = g0[j + 512] * (sigf(sc) * rbn) + bt0[j + 512];
    cbuf[idx] = cv;
    hb[idx] = f2b(hv);
}

// ------- fused attention score + softmax: one block per batch row -------
__global__ __launch_bounds__(256)
void attn_softmax(const ushort* __restrict__ fa, const float* __restrict__ combo,
                  const float* __restrict__ Wv, float* __restrict__ alpha,
                  float* __restrict__ alphas_out, const int* __restrict__ clen,
                  int t) {
    int b = blockIdx.x;
    int tid = threadIdx.x;
    int w = tid >> 6, l = tid & 63;
    __shared__ float eS[256];
    __shared__ float red[256];
    const float* hap = combo + (size_t)b * 2560;   // ha part of combo row
    float ha8[8], wv8[8];
#pragma unroll
    for (int i = 0; i < 8; i++) { ha8[i] = hap[l * 8 + i]; wv8[i] = Wv[l * 8 + i]; }
    eS[tid] = -1e30f;
    __syncthreads();
    const ushort* fab = fa + (size_t)b * P_ * NF_;
    for (int p = w; p < P_; p += 4) {
        const ushort* fp = fab + (size_t)p * NF_ + l * 8;
        ushort4 u0 = *(const ushort4*)fp;
        ushort4 u1 = *(const ushort4*)(fp + 4);
        float s = 0.0f, v;
        v = b2f(u0.x) + ha8[0]; v = v > 0.f ? v : 0.f; s = fmaf(v, wv8[0], s);
        v = b2f(u0.y) + ha8[1]; v = v > 0.f ? v : 0.f; s = fmaf(v, wv8[1], s);
        v = b2f(u0.z) + ha8[2]; v = v > 0.f ? v : 0.f; s = fmaf(v, wv8[2], s);
        v = b2f(u0.w) + ha8[3]; v = v > 0.f ? v : 0.f; s = fmaf(v, wv8[3], s);
        v = b2f(u1.x) + ha8[4]; v = v > 0.f ? v : 0.f; s = fmaf(v, wv8[4], s);
        v = b2f(u1.y) + ha8[5]; v = v > 0.f ? v : 0.f; s = fmaf(v, wv8[5], s);
        v = b2f(u1.z) + ha8[6]; v = v > 0.f ? v : 0.f; s = fmaf(v, wv8[6], s);
        v = b2f(u1.w) + ha8[7]; v = v > 0.f ? v : 0.f; s = fmaf(v, wv8[7], s);
#pragma unroll
        for (int off = 32; off > 0; off >>= 1) s += __shfl_down(s, off, 64);
        if (l == 0) eS[p] = s;
    }
    __syncthreads();
    float ev = eS[tid];
    red[tid] = ev;
    __syncthreads();
    for (int s = 128; s > 0; s >>= 1) {
        if (tid < s) red[tid] = fmaxf(red[tid], red[tid + s]);
        __syncthreads();
    }
    float mx = red[0];
    __syncthreads();
    float ex = expf(ev - mx);
    red[tid] = ex;
    __syncthreads();
    for (int s = 128; s > 0; s >>= 1) {
        if (tid < s) red[tid] += red[tid + s];
        __syncthreads();
    }
    float inv = 1.0f / red[0];
    if (tid < P_) {
        float a = ex * inv;
        alpha[b * P_ + tid] = a;
        float m = (t < clen[b] - 1) ? 1.0f : 0.0f;
        alphas_out[((size_t)b * T_ + t) * P_ + tid] = a * m;
    }
}

// ------- fused context + input-gate: gctxb = bf16(sig(glog) * (alpha @ enc)) ---
template <int BF>
__global__ __launch_bounds__(256)
void context_gate(const void* __restrict__ encv, const float* __restrict__ alpha,
                  const float* __restrict__ combo, ushort* __restrict__ gctxb) {
    __shared__ float al[P_];
    int b = blockIdx.x >> 1;
    int f0 = ((blockIdx.x & 1) << 10) + threadIdx.x * 4;
    if (threadIdx.x < P_) al[threadIdx.x] = alpha[b * P_ + threadIdx.x];
    __syncthreads();
    float s0 = 0.f, s1 = 0.f, s2 = 0.f, s3 = 0.f;
    if (BF) {
        const ushort* ep = (const ushort*)encv + (size_t)b * P_ * F_ + f0;
#pragma unroll 2
        for (int p = 0; p < P_; p++) {
            ushort4 u = *(const ushort4*)(ep + (size_t)p * F_);
            float a = al[p];
            s0 = fmaf(a, b2f(u.x), s0);
            s1 = fmaf(a, b2f(u.y), s1);
            s2 = fmaf(a, b2f(u.z), s2);
            s3 = fmaf(a, b2f(u.w), s3);
        }
    } else {
        const float* ep = (const float*)encv + (size_t)b * P_ * F_ + f0;
#pragma unroll 2
        for (int p = 0; p < P_; p++) {
            float4 u = *(const float4*)(ep + (size_t)p * F_);
            float a = al[p];
            s0 = fmaf(a, u.x, s0);
            s1 = fmaf(a, u.y, s1);
            s2 = fmaf(a, u.z, s2);
            s3 = fmaf(a, u.w, s3);
        }
    }
    float4 g4 = *(const float4*)(combo + (size_t)b * 2560 + 512 + f0);
    ushort4 o;
    o.x = f2b(sigf(g4.x) * s0);
    o.y = f2b(sigf(g4.y) * s1);
    o.z = f2b(sigf(g4.z) * s2);
    o.w = f2b(sigf(g4.w) * s3);
    *(ushort4*)(gctxb + (size_t)b * F_ + f0) = o;
}

// ---------------- LSTM pointwise (sums nz gate partials) ----------------
__global__ __launch_bounds__(256)
void lstm_kernel(const float* __restrict__ gatesA, const float* __restrict__ embproj,
                 const float* __restrict__ bih, const float* __restrict__ bhh,
                 float* __restrict__ c, ushort* __restrict__ hb, int t, int nz) {
    int idx = blockIdx.x * 256 + threadIdx.x;   // B*H
    int b = idx >> 9, j = idx & (H_ - 1);
    const float* ep = embproj + ((size_t)b * T_ + t) * 4 * H_;
    float g4[4];
#pragma unroll
    for (int q = 0; q < 4; q++) {
        int col = j + q * H_;
        float s = ep[col] + bih[col] + bhh[col];
        for (int z = 0; z < nz; z++)
            s += gatesA[((size_t)z * B_ + b) * 4 * H_ + col];
        g4[q] = s;
    }
    float cn = sigf(g4[1]) * c[idx] + sigf(g4[0]) * tanhf(g4[2]);
    float hn = sigf(g4[3]) * tanhf(cn);
    c[idx] = cn;
    hb[idx] = f2b(hn);
}

extern "C" void kernel_launch(void* const* d_in, const int* in_sizes, int n_in,
                              void* d_out, int out_size, void* d_ws, size_t ws_size,
                              hipStream_t stream) {
    const float* enc = (const float*)d_in[0];
    const float* emb = (const float*)d_in[1];
    const float* Wfa = (const float*)d_in[2];
    const float* bfa = (const float*)d_in[3];
    const float* Wha = (const float*)d_in[4];
    const float* bha = (const float*)d_in[5];
    const float* Wv  = (const float*)d_in[6];
    const float* Wh0 = (const float*)d_in[8];
    const float* bh0 = (const float*)d_in[9];
    const float* Wc0 = (const float*)d_in[10];
    const float* bc0 = (const float*)d_in[11];
    const float* gh  = (const float*)d_in[12];
    const float* bth = (const float*)d_in[13];
    const float* gc  = (const float*)d_in[14];
    const float* btc = (const float*)d_in[15];
    const float* Wfb = (const float*)d_in[16];
    const float* bfb = (const float*)d_in[17];
    const float* Wih = (const float*)d_in[18];
    const float* Whh = (const float*)d_in[19];
    const float* bih = (const float*)d_in[20];
    const float* bhh = (const float*)d_in[21];
    const float* Wfc = (const float*)d_in[22];
    const float* bfc = (const float*)d_in[23];
    const int* gt   = (const int*)d_in[24];
    const int* clen = (const int*)d_in[25];

    float* out_pred  = (float*)d_out;                       // (B,T,V)
    float* out_alpha = out_pred + (size_t)B_ * T_ * V_;     // (B,T,P)

    char* wp = (char*)d_ws;
    auto alloc = [&](size_t bytes) {
        char* p = wp;
        wp += (bytes + 255) & ~(size_t)255;
        return p;
    };
    float*  feat    = (float*)alloc((size_t)B_ * F_ * 4);
    float*  cbuf    = (float*)alloc((size_t)B_ * H_ * 4);
    float*  combo   = (float*)alloc((size_t)B_ * 2560 * 4);
    float*  alphab  = (float*)alloc((size_t)B_ * P_ * 4);
    float*  gatesA  = (float*)alloc((size_t)4 * B_ * 4 * H_ * 4);
    float*  embproj = (float*)alloc((size_t)B_ * T_ * 4 * H_ * 4);
    float*  hcpart  = (float*)alloc((size_t)4 * B_ * 1024 * 4);
    float*  bcomb   = (float*)alloc(2560 * 4);
    float*  b0comb  = (float*)alloc(1024 * 4);
    float*  g0comb  = (float*)alloc(1024 * 4);
    float*  bt0comb = (float*)alloc(1024 * 4);
    ushort* hb      = (ushort*)alloc((size_t)B_ * H_ * 2);
    ushort* gctxb   = (ushort*)alloc((size_t)B_ * F_ * 2);
    ushort* embxb   = (ushort*)alloc((size_t)B_ * T_ * E_ * 2);
    ushort* fattb   = (ushort*)alloc((size_t)B_ * P_ * NF_ * 2);
    ushort* featb   = (ushort*)alloc((size_t)B_ * F_ * 2);
    ushort* Wfab    = (ushort*)alloc((size_t)NF_ * F_ * 2);
    ushort* WihEb   = (ushort*)alloc((size_t)4 * H_ * E_ * 2);
    ushort* WihFb   = (ushort*)alloc((size_t)4 * H_ * F_ * 2);
    ushort* Whhb    = (ushort*)alloc((size_t)4 * H_ * H_ * 2);
    ushort* Wcombb  = (ushort*)alloc((size_t)2560 * H_ * 2);
    ushort* W0comb  = (ushort*)alloc((size_t)1024 * F_ * 2);
    ushort* Wfcb    = (ushort*)alloc((size_t)NPAD_ * H_ * 2);
    ushort* encb    = (ushort*)alloc((size_t)B_ * P_ * F_ * 2);
    const bool big = ((size_t)(wp - (char*)d_ws) <= ws_size);

    auto castM = [&](const float* s, ushort* d, long long rows, int cols, int sld, int srows) {
        long long total = rows * (long long)cols;
        cast_mat<<<(int)((total + 1023) / 1024), 256, 0, stream>>>(s, d, total, cols, sld, srows);
    };

    // ---- one-time casts & bias concats ----
    if (big) castM(enc, encb, (long long)B_ * P_, F_, F_, B_ * P_);
    castM(Wfa, Wfab, NF_, F_, F_, NF_);
    castM(Wih, WihEb, 4 * H_, E_, E_ + F_, 4 * H_);
    castM(Wih + E_, WihFb, 4 * H_, F_, E_ + F_, 4 * H_);
    castM(Whh, Whhb, 4 * H_, H_, H_, 4 * H_);
    castM(Wha, Wcombb, NF_, H_, H_, NF_);
    castM(Wfb, Wcombb + (size_t)NF_ * H_, F_, H_, H_, F_);
    castM(Wh0, W0comb, H_, F_, F_, H_);
    castM(Wc0, W0comb + (size_t)H_ * F_, H_, F_, F_, H_);
    castM(Wfc, Wfcb, NPAD_, H_, H_, V_);
    hipMemcpyAsync(bcomb, bha, NF_ * 4, hipMemcpyDeviceToDevice, stream);
    hipMemcpyAsync(bcomb + NF_, bfb, F_ * 4, hipMemcpyDeviceToDevice, stream);
    hipMemcpyAsync(b0comb, bh0, H_ * 4, hipMemcpyDeviceToDevice, stream);
    hipMemcpyAsync(b0comb + H_, bc0, H_ * 4, hipMemcpyDeviceToDevice, stream);
    hipMemcpyAsync(g0comb, gh, H_ * 4, hipMemcpyDeviceToDevice, stream);
    hipMemcpyAsync(g0comb + H_, gc, H_ * 4, hipMemcpyDeviceToDevice, stream);
    hipMemcpyAsync(bt0comb, bth, H_ * 4, hipMemcpyDeviceToDevice, stream);
    hipMemcpyAsync(bt0comb + H_, btc, H_ * 4, hipMemcpyDeviceToDevice, stream);

    // ---- init state: mean -> bf16 -> [Wh0;Wc0] MFMA (z=4) -> finalize ----
    mean_kernel<<<B_ * 8, 256, 0, stream>>>(enc, feat);
    castM(feat, featb, B_, F_, F_, B_);
    mfma_gemm<32, MEPI_NONE, 0><<<dim3(1024 / 128, B_ / 32, 4), 256, 0, stream>>>(
        featb, F_, W0comb, F_, F_, nullptr, 0, nullptr, 0, 0,
        nullptr, hcpart, 1024, B_, 1024, nullptr, 0);
    h0c0_final<<<(B_ * H_) / 256, 256, 0, stream>>>(hcpart, b0comb, g0comb, bt0comb, cbuf, hb);
    gather_b<<<(B_ * T_ * E_) / 1024, 256, 0, stream>>>(emb, gt, embxb);

    // ---- feat_att (bf16 out) ----
    if (big) {
        mfma_gemm<128, MEPI_BIASB, 0><<<dim3(NF_ / 128, (B_ * P_) / 128, 1), 256, 0, stream>>>(
            encb, F_, Wfab, F_, F_, nullptr, 0, nullptr, 0, 0,
            bfa, fattb, NF_, B_ * P_, NF_, nullptr, 0);
    } else {
        gemm_xwt<EPI_BIASB><<<dim3(NF_ / 64, (B_ * P_) / 64), 256, 0, stream>>>(
            enc, F_, Wfa, F_, bfa, (float*)fattb, NF_, B_ * P_, NF_, F_);
    }
    // ---- embproj = embx @ WihE^T (fp32 out) ----
    mfma_gemm<128, MEPI_NONE, 0><<<dim3((4 * H_) / 128, (B_ * T_) / 128, 1), 256, 0, stream>>>(
        embxb, E_, WihEb, E_, E_, nullptr, 0, nullptr, 0, 0,
        nullptr, embproj, 4 * H_, B_ * T_, 4 * H_, nullptr, 0);

    // ---- recurrent scan ----
    for (int t = 0; t < T_; t++) {
        // combo = h @ [Wha;Wfb]^T + [bha;bfb]   (128 x 2560)
        mfma_gemm<32, MEPI_BIAS, 0><<<dim3(2560 / 128, B_ / 32, 1), 256, 0, stream>>>(
            hb, H_, Wcombb, H_, H_, nullptr, 0, nullptr, 0, 0,
            bcomb, combo, 2560, B_, 2560, nullptr, 0);
        attn_softmax<<<B_, 256, 0, stream>>>(fattb, combo, Wv, alphab, out_alpha, clen, t);
        if (big) context_gate<1><<<B_ * 2, 256, 0, stream>>>(encb, alphab, combo, gctxb);
        else     context_gate<0><<<B_ * 2, 256, 0, stream>>>(enc, alphab, combo, gctxb);
        mfma_gemm<32, MEPI_NONE, 1><<<dim3((4 * H_) / 128, B_ / 32, 4), 256, 0, stream>>>(
            gctxb, F_, WihFb, F_, F_, hb, H_, Whhb, H_, H_,
            nullptr, gatesA, 4 * H_, B_, 4 * H_, nullptr, 0);
        lstm_kernel<<<(B_ * H_) / 256, 256, 0, stream>>>(
            gatesA, embproj, bih, bhh, cbuf, hb, t, 4);
        mfma_gemm<64, MEPI_MASK, 0><<<dim3(NPAD_ / 128, B_ / 64, 1), 256, 0, stream>>>(
            hb, H_, Wfcb, H_, H_, nullptr, 0, nullptr, 0, 0,
            bfc, out_pred + (size_t)t * V_, (long long)T_ * V_, B_, V_,
            clen, t);
    }
}